// Round 7
// baseline (8210.087 us; speedup 1.0000x reference)
//
#include <hip/hip_runtime.h>
#include <hip/hip_fp16.h>

#define T_TOK 256
#define NNODE 2049
#define HENC  256
#define DHID  512
#define DIN   800
#define G4    1024
#define DG4   2048

typedef _Float16 f16;
typedef _Float16 f16x2 __attribute__((ext_vector_type(2)));
typedef short    bf16x8 __attribute__((ext_vector_type(8)));
typedef float    f32x4  __attribute__((ext_vector_type(4)));

static __device__ __forceinline__ float sigm(float x){ return 1.0f/(1.0f+__expf(-x)); }
static __device__ __forceinline__ float tanhfast(float x){ return 1.0f - 2.0f/(__expf(2.0f*x)+1.0f); }

static __device__ __forceinline__ unsigned short f2bf(float x){
    unsigned u = __builtin_bit_cast(unsigned, x);
    unsigned r = (u + 0x7fffu + ((u>>16)&1u)) >> 16;
    return (unsigned short)r;
}
static __device__ __forceinline__ unsigned packh2(float a, float b){
    f16 ha = (f16)a, hb = (f16)b;
    unsigned short ua = __builtin_bit_cast(unsigned short, ha);
    unsigned short ub = __builtin_bit_cast(unsigned short, hb);
    return (unsigned)ua | ((unsigned)ub << 16);
}
static __device__ __forceinline__ float fdot2(unsigned wpk, unsigned hpk, float c){
#if __has_builtin(__builtin_amdgcn_fdot2)
    return __builtin_amdgcn_fdot2(__builtin_bit_cast(f16x2, wpk),
                                  __builtin_bit_cast(f16x2, hpk), c, false);
#else
    float d;
    asm volatile("v_dot2_f32_f16 %0, %1, %2, %3" : "=v"(d) : "v"(wpk), "v"(hpk), "v"(c));
    return d;
#endif
}

// opaque (non-rematerializable) 16B load
static __device__ __forceinline__ uint4 ldw_opaque(const uint4* p){
    uint4 r;
    asm volatile("global_load_dwordx4 %0, %1, off\n\ts_waitcnt vmcnt(0)"
                 : "=v"(r) : "v"(p));
    return r;
}

// LDS h layout: f16 slot for unit n = uint4 index (((n>>3)&1)*16 + (n>>4)), lane (n&7)
static __device__ __forceinline__ int hslot(int n){
    return ((((n>>3)&1)*16 + (n>>4))<<3) | (n&7);
}

// ---------------- embedding gather -> bf16 ----------------
__global__ void k_embed(const int* __restrict__ lat,
                        const float* __restrict__ form, const float* __restrict__ lemma,
                        const float* __restrict__ tag,  const float* __restrict__ feats,
                        unsigned short* __restrict__ embB){
    int n = blockIdx.x;
    const int* L = lat + n*11;
    int i0 = L[0], i1 = L[1], i2 = L[2];
    for (int c = threadIdx.x; c < DIN; c += blockDim.x){
        float v;
        if (c < 300)      v = form[i0*300 + c];
        else if (c < 600) v = lemma[i1*300 + (c-300)];
        else if (c < 700) v = tag[i2*100 + (c-600)];
        else {
            float s = 0.f;
            #pragma unroll
            for (int j=0;j<6;++j) s += feats[L[3+j]*100 + (c-700)];
            v = s * (1.0f/6.0f);
        }
        embB[n*DIN + c] = f2bf(v);
    }
}

__global__ void k_f32_to_bf16(const float* __restrict__ src, unsigned short* __restrict__ dst, int n){
    int i = blockIdx.x*blockDim.x + threadIdx.x;
    if (i < n) dst[i] = f2bf(src[i]);
}

// pack Whh: worker b=(d*4+p), thread t (0..1023): u=t>>4, cq=t&15.
// Gate g: row = g*256 + p*64 + u, cols cq*16 + k*8 + 2c (k=0,1; c=0..3)
// -> wreg4[(b*8 + g*2 + k)*1024 + t]
__global__ void k_pack_whh_v5(const float* __restrict__ wf, const float* __restrict__ wb,
                              uint4* __restrict__ wreg4){
    int id = blockIdx.x*blockDim.x + threadIdx.x;   // 8 blocks x 1024
    int b = id >> 10, t = id & 1023;
    int d = b >> 2, p = b & 3;
    const float* W = d ? wb : wf;
    int u = t >> 4, cq = t & 15;
    for (int g=0; g<4; ++g){
        const float* R = W + (size_t)(g*256 + p*64 + u)*256 + cq*16;
        for (int k=0; k<2; ++k){
            uint4 v;
            v.x = packh2(R[k*8+0], R[k*8+1]);
            v.y = packh2(R[k*8+2], R[k*8+3]);
            v.z = packh2(R[k*8+4], R[k*8+5]);
            v.w = packh2(R[k*8+6], R[k*8+7]);
            wreg4[((size_t)(b*8 + g*2 + k))*1024 + t] = v;
        }
    }
}

// ---------------- bf16 MFMA GEMM: C[M][Nc] = A[M][K] * B[Nc][K]^T (+bias) ----------------
__global__ __launch_bounds__(256) void k_gemm_bf16(const unsigned short* __restrict__ A,
                                                   const unsigned short* __restrict__ B,
                                                   float* __restrict__ C,
                                                   const float* __restrict__ bias,
                                                   int M, int Nc, int K){
    __shared__ unsigned short As[64][40];
    __shared__ unsigned short Bs[64][40];
    int m0 = blockIdx.x*64, n0 = blockIdx.y*64;
    int t = threadIdx.x, w = t>>6, lane = t&63;
    f32x4 acc[4];
    #pragma unroll
    for (int i=0;i<4;++i) acc[i] = (f32x4){0.f,0.f,0.f,0.f};
    int rowl = t>>2, kb0 = (t&3)*8;
    for (int k0=0; k0<K; k0+=32){
        uint4 av;
        int ar = m0 + rowl;
        if (ar < M) av = *(const uint4*)(A + (size_t)ar*K + k0 + kb0);
        else { av.x=av.y=av.z=av.w=0u; }
        *(uint4*)&As[rowl][kb0] = av;
        *(uint4*)&Bs[rowl][kb0] = *(const uint4*)(B + (size_t)(n0+rowl)*K + k0 + kb0);
        __syncthreads();
        int arow = w*16 + (lane&15), kk = (lane>>4)*8;
        bf16x8 af = *(const bf16x8*)&As[arow][kk];
        #pragma unroll
        for (int nt=0;nt<4;++nt){
            bf16x8 bf = *(const bf16x8*)&Bs[nt*16 + (lane&15)][kk];
            acc[nt] = __builtin_amdgcn_mfma_f32_16x16x32_bf16(af, bf, acc[nt], 0,0,0);
        }
        __syncthreads();
    }
    #pragma unroll
    for (int nt=0;nt<4;++nt){
        int col = n0 + nt*16 + (lane&15);
        float bb = bias ? bias[col] : 0.0f;
        #pragma unroll
        for (int r=0;r<4;++r){
            int row = m0 + w*16 + (lane>>4)*4 + r;
            if (row < M) C[(size_t)row*Nc + col] = acc[nt][r] + bb;
        }
    }
}

// ---------------- sequential bi-LSTM scan v7 ----------------
// 8 workers (4 per direction); weights resident (8 uint4/thread, proven r6).
// Per step: dots -> barrier A -> {wave0: update+store+flag | waves1-3: spin+gather}
// -> barrier D. h LDS layout k-major (2-way max bank aliasing).
#define LOADW(g,k) const uint4 W##g##_##k = ldw_opaque(&wreg4[((size_t)(b*8 + g*2 + k))*1024 + t]);

#define G8(A, P, Q) A = fdot2(P.x,hv0.x,A); A = fdot2(P.y,hv0.y,A); \
                    A = fdot2(P.z,hv0.z,A); A = fdot2(P.w,hv0.w,A); \
                    A = fdot2(Q.x,hv1.x,A); A = fdot2(Q.y,hv1.y,A); \
                    A = fdot2(Q.z,hv1.z,A); A = fdot2(Q.w,hv1.w,A);

__global__ __launch_bounds__(1024)
void k_lstm_scan(const uint4* __restrict__ wreg4,
                 const float* __restrict__ XgF,
                 const float* __restrict__ XgB,
                 int* __restrict__ flg,
                 float* __restrict__ xh,
                 float* __restrict__ encoded,
                 float* __restrict__ h0,
                 float* __restrict__ c0){
    __shared__ uint4 sH4[32];          // 256 h as f16, k-major layout
    __shared__ float sG[256];
    int bid = blockIdx.x;
    int d = bid & 7, p = bid >> 3;
    if (d >= 2) return;                // workers: bid 0,8,16,24 (d0) / 1,9,17,25 (d1)
    int b = d*4 + p;
    int t = threadIdx.x;
    int cq = t & 15;
    int wv = t >> 6;
    const float* Xg = d ? XgB : XgF;
    unsigned* sH32 = (unsigned*)sH4;
    f16* sHh = (f16*)sH4;

    LOADW(0,0) LOADW(0,1) LOADW(1,0) LOADW(1,1)
    LOADW(2,0) LOADW(2,1) LOADW(3,0) LOADW(3,1)

    if (t < 128) sH32[t] = 0u;
    float c_reg = 0.0f;
    __syncthreads();

    int node  = d ? (NNODE-1) : 0;
    int stepd = d ? -1 : 1;
    // partner worker index for gather waves 1..3
    int q  = (wv >= 1 && wv <= 3) ? ((wv-1) + ((wv-1) >= p ? 1 : 0)) : 0;
    int qf = d*4 + q;

    for (int s=0; s<NNODE; ++s){
        // gate-x inputs for this node (wave 0 = update threads, coalesced)
        float xi=0.f, xf=0.f, xgg=0.f, xo=0.f;
        if (wv == 0){
            const float* xr = Xg + (size_t)node*G4 + p*64 + t;
            xi  = xr[0];
            xf  = xr[256];
            xgg = xr[512];
            xo  = xr[768];
        }
        uint4 hv0 = sH4[cq];
        uint4 hv1 = sH4[cq + 16];
        float a0=0.f,a1=0.f,a2=0.f,a3=0.f;
        G8(a0, W0_0, W0_1)
        G8(a1, W1_0, W1_1)
        G8(a2, W2_0, W2_1)
        G8(a3, W3_0, W3_1)
        a0 += __shfl_xor(a0,1); a0 += __shfl_xor(a0,2); a0 += __shfl_xor(a0,4); a0 += __shfl_xor(a0,8);
        a1 += __shfl_xor(a1,1); a1 += __shfl_xor(a1,2); a1 += __shfl_xor(a1,4); a1 += __shfl_xor(a1,8);
        a2 += __shfl_xor(a2,1); a2 += __shfl_xor(a2,2); a2 += __shfl_xor(a2,4); a2 += __shfl_xor(a2,8);
        a3 += __shfl_xor(a3,1); a3 += __shfl_xor(a3,2); a3 += __shfl_xor(a3,4); a3 += __shfl_xor(a3,8);
        if (cq == 0){
            int u = t >> 4;
            sG[u]       = a0;
            sG[64 + u]  = a1;
            sG[128 + u] = a2;
            sG[192 + u] = a3;
        }
        __syncthreads();                               // A: sG ready
        if (wv == 0){
            float gi = sG[t] + xi, gf = sG[64+t] + xf;
            float gg = sG[128+t] + xgg, go = sG[192+t] + xo;
            float c = sigm(gf)*c_reg + sigm(gi)*tanhfast(gg);
            c_reg = c;
            float h = sigm(go)*tanhfast(c);
            __hip_atomic_store(&xh[((b*2) + (s&1))*64 + t], h,
                               __ATOMIC_RELAXED, __HIP_MEMORY_SCOPE_AGENT);
            if (t == 0){
                // release: compiler drains this wave's xh stores (vmcnt) first
                __hip_atomic_store(&flg[b], s+1, __ATOMIC_RELEASE, __HIP_MEMORY_SCOPE_AGENT);
            }
            sHh[hslot(p*64 + t)] = (f16)h;
            encoded[(size_t)node*DHID + d*HENC + p*64 + t] = h;
            if (s == NNODE-1){ h0[d*HENC + p*64 + t] = h; c0[d*HENC + p*64 + t] = c; }
        } else if (wv < 4){
            long iters = 0;
            while (__hip_atomic_load(&flg[qf], __ATOMIC_ACQUIRE, __HIP_MEMORY_SCOPE_AGENT) < s+1){
                if (++iters > (1L<<27)) break;         // safety valve vs. hang
            }
            float hp = xh[(qf*2 + (s&1))*64 + (t&63)];
            sHh[hslot(q*64 + (t&63))] = (f16)hp;
        }
        __syncthreads();                               // D: full h ready for next step
        node += stepd;
    }
}

// Kd = dec_whh @ h0 + dec_b
__global__ void k_dec_const(const float* __restrict__ dec_whh, const float* __restrict__ dec_b,
                            const float* __restrict__ h0, float* __restrict__ Kd){
    __shared__ float sh[512];
    int t = threadIdx.x;
    int r = blockIdx.x*256 + t;
    sh[t] = h0[t]; sh[256+t] = h0[256+t];
    __syncthreads();
    float a = 0.f;
    const float* Wr = dec_whh + (size_t)r*512;
    for (int k=0;k<512;++k) a += Wr[k]*sh[k];
    Kd[r] = a + dec_b[r];
}

// decoder h for every possible ptr node
__global__ void k_hall(const float* __restrict__ G, const float* __restrict__ Kd,
                       const float* __restrict__ c0, float* __restrict__ Hall){
    int n = blockIdx.x, u = threadIdx.x;
    const float* g = G + (size_t)n*DG4;
    float gi = g[u]        + Kd[u];
    float gf = g[512+u]    + Kd[512+u];
    float gg = g[1024+u]   + Kd[1024+u];
    float go = g[1536+u]   + Kd[1536+u];
    float c  = sigm(gf)*c0[u] + sigm(gi)*tanhfast(gg);
    Hall[(size_t)n*DHID + u] = sigm(go)*tanhfast(c);
}

// S[i][p][c] = encoded[cand(i,c)] . Hall[prev(i,p)]
__global__ __launch_bounds__(256) void k_scores(const float* __restrict__ encoded,
                                                const float* __restrict__ Hall,
                                                float* __restrict__ S){
    __shared__ float sE[8][512];
    __shared__ float sHp[8][512];
    int i = blockIdx.x, t = threadIdx.x;
    for (int idx = t; idx < 8*512; idx += 256){
        int r = idx >> 9, c = idx & 511;
        int cand = 1 + i*8 + r;
        sE[r][c] = encoded[(size_t)cand*DHID + c];
        int prev = (i==0) ? 0 : (1 + (i-1)*8 + r);
        sHp[r][c] = Hall[(size_t)prev*DHID + c];
    }
    __syncthreads();
    int w = t>>6, lane = t&63;
    for (int q=0;q<16;++q){
        int pi = w*16 + q, p = pi>>3, c = pi&7;
        float v = 0.f;
        #pragma unroll
        for (int j=0;j<8;++j) v += sE[c][lane*8+j]*sHp[p][lane*8+j];
        #pragma unroll
        for (int off=32; off; off>>=1) v += __shfl_xor(v, off);
        if (lane==0) S[i*64 + p*8 + c] = v;
    }
}

// sequential pointer chain + loss
__global__ __launch_bounds__(256) void k_decode(const float* __restrict__ S, float* __restrict__ out){
    __shared__ float nll[2048];
    __shared__ int   cst[2048];
    __shared__ int   path[256];
    __shared__ float wsum[4];
    int t = threadIdx.x;
    for (int p=0;p<8;++p){
        const float* s = S + t*64 + p*8;
        float m = s[0]; int am = 0;
        #pragma unroll
        for (int c=1;c<8;++c){ float v = s[c]; if (v > m){ m = v; am = c; } }
        float e = 0.f;
        #pragma unroll
        for (int c=0;c<8;++c) e += __expf(s[c]-m);
        float lse = m + __logf(e);
        nll[t*8+p] = lse - s[0];
        cst[t*8+p] = am;
    }
    __syncthreads();
    if (t == 0){
        int p = 0;
        for (int i=0;i<256;++i){
            int idx = i*8 + p;
            path[i] = idx;
            int c = cst[idx];
            out[i+1] = (float)(1 + i*8 + c);
            p = c;
        }
        out[0] = 0.0f;
    }
    __syncthreads();
    float v = nll[path[t]];
    #pragma unroll
    for (int off=32; off; off>>=1) v += __shfl_xor(v, off);
    if ((t&63)==0) wsum[t>>6] = v;
    __syncthreads();
    if (t==0) out[257] = (wsum[0]+wsum[1]+wsum[2]+wsum[3]) * (1.0f/256.0f);
}

extern "C" void kernel_launch(void* const* d_in, const int* in_sizes, int n_in,
                              void* d_out, int out_size, void* d_ws, size_t ws_size,
                              hipStream_t stream){
    (void)in_sizes; (void)n_in; (void)out_size; (void)ws_size;
    const int*   lattice  = (const int*)  d_in[0];
    const float* form     = (const float*)d_in[2];
    const float* lemma    = (const float*)d_in[3];
    const float* tag      = (const float*)d_in[4];
    const float* feats    = (const float*)d_in[5];
    const float* wih_f    = (const float*)d_in[6];
    const float* whh_f    = (const float*)d_in[7];
    const float* b_f      = (const float*)d_in[8];
    const float* wih_b    = (const float*)d_in[9];
    const float* whh_b    = (const float*)d_in[10];
    const float* b_b      = (const float*)d_in[11];
    const float* dwih     = (const float*)d_in[12];
    const float* dwhh     = (const float*)d_in[13];
    const float* db       = (const float*)d_in[14];
    float* out = (float*)d_out;

    char* ws = (char*)d_ws;
    size_t o = 0;
    auto alloc = [&](size_t bytes)->char*{ char* p = ws + o; o = (o + bytes + 255) & ~(size_t)255; return p; };
    int*            flg    = (int*)alloc(256);                      // 8 flags
    float*          xh     = (float*)alloc(4096);                   // [8][2][64] f32
    unsigned short* embB   = (unsigned short*)alloc((size_t)NNODE*DIN*2);
    unsigned short* wihfB  = (unsigned short*)alloc((size_t)G4*DIN*2);
    unsigned short* wihbB  = (unsigned short*)alloc((size_t)G4*DIN*2);
    unsigned short* dwihB  = (unsigned short*)alloc((size_t)DG4*DIN*2);
    uint4*          wreg4  = (uint4*)alloc((size_t)8*8*1024*16);
    float*          XgF    = (float*)alloc((size_t)NNODE*G4*4);
    float*          XgB    = (float*)alloc((size_t)NNODE*G4*4);
    float*          Graw   = (float*)alloc((size_t)NNODE*DG4*4);
    float*          enc    = (float*)alloc((size_t)NNODE*DHID*4);
    float*          h0     = (float*)alloc(512*4);
    float*          c0     = (float*)alloc(512*4);
    float*          Kd     = (float*)alloc(2048*4);
    float*          Hall   = (float*)alloc((size_t)NNODE*DHID*4);
    float*          Sbuf   = (float*)alloc((size_t)256*64*4);

    // reset sync state every launch (graph-capture safe)
    hipMemsetAsync(d_ws, 0, 8192, stream);

    k_f32_to_bf16<<<(G4*DIN+255)/256, 256, 0, stream>>>(wih_f, wihfB, G4*DIN);
    k_f32_to_bf16<<<(G4*DIN+255)/256, 256, 0, stream>>>(wih_b, wihbB, G4*DIN);
    k_f32_to_bf16<<<(DG4*DIN+255)/256, 256, 0, stream>>>(dwih, dwihB, DG4*DIN);
    k_pack_whh_v5<<<8, 1024, 0, stream>>>(whh_f, whh_b, wreg4);
    k_embed<<<NNODE, 256, 0, stream>>>(lattice, form, lemma, tag, feats, embB);

    dim3 gE((NNODE+63)/64, G4/64);
    k_gemm_bf16<<<gE, 256, 0, stream>>>(embB, wihfB, XgF, b_f, NNODE, G4, DIN);
    k_gemm_bf16<<<gE, 256, 0, stream>>>(embB, wihbB, XgB, b_b, NNODE, G4, DIN);
    dim3 gD((NNODE+63)/64, DG4/64);
    k_gemm_bf16<<<gD, 256, 0, stream>>>(embB, dwihB, Graw, nullptr, NNODE, DG4, DIN);

    k_lstm_scan<<<32, 1024, 0, stream>>>(wreg4, XgF, XgB, flg, xh, enc, h0, c0);

    k_dec_const<<<8, 256, 0, stream>>>(dwhh, db, h0, Kd);
    k_hall<<<NNODE, 512, 0, stream>>>(Graw, Kd, c0, Hall);
    k_scores<<<256, 256, 0, stream>>>(enc, Hall, Sbuf);
    k_decode<<<1, 256, 0, stream>>>(Sbuf, out);
}

// Round 8
// 4679.215 us; speedup vs baseline: 1.7546x; 1.7546x over previous
//
#include <hip/hip_runtime.h>
#include <hip/hip_fp16.h>

#define T_TOK 256
#define NNODE 2049
#define HENC  256
#define DHID  512
#define DIN   800
#define G4    1024
#define DG4   2048

typedef _Float16 f16;
typedef _Float16 f16x2 __attribute__((ext_vector_type(2)));
typedef short    bf16x8 __attribute__((ext_vector_type(8)));
typedef float    f32x4  __attribute__((ext_vector_type(4)));

static __device__ __forceinline__ float sigm(float x){ return 1.0f/(1.0f+__expf(-x)); }
static __device__ __forceinline__ float tanhfast(float x){ return 1.0f - 2.0f/(__expf(2.0f*x)+1.0f); }

static __device__ __forceinline__ unsigned short f2bf(float x){
    unsigned u = __builtin_bit_cast(unsigned, x);
    unsigned r = (u + 0x7fffu + ((u>>16)&1u)) >> 16;
    return (unsigned short)r;
}
static __device__ __forceinline__ unsigned packh2(float a, float b){
    f16 ha = (f16)a, hb = (f16)b;
    unsigned short ua = __builtin_bit_cast(unsigned short, ha);
    unsigned short ub = __builtin_bit_cast(unsigned short, hb);
    return (unsigned)ua | ((unsigned)ub << 16);
}
static __device__ __forceinline__ float fdot2(unsigned wpk, unsigned hpk, float c){
#if __has_builtin(__builtin_amdgcn_fdot2)
    return __builtin_amdgcn_fdot2(__builtin_bit_cast(f16x2, wpk),
                                  __builtin_bit_cast(f16x2, hpk), c, false);
#else
    float d;
    asm volatile("v_dot2_f32_f16 %0, %1, %2, %3" : "=v"(d) : "v"(wpk), "v"(hpk), "v"(c));
    return d;
#endif
}

// opaque (non-rematerializable) 16B load
static __device__ __forceinline__ uint4 ldw_opaque(const uint4* p){
    uint4 r;
    asm volatile("global_load_dwordx4 %0, %1, off\n\ts_waitcnt vmcnt(0)"
                 : "=v"(r) : "v"(p));
    return r;
}

// k-major h LDS layout: logical uint4 i (units 8i..8i+7) at physical (i&7)*4 + (i>>3).
// dword slot for even unit n: p_i*4 + ((n&7)>>1)
static __device__ __forceinline__ int dwslot(int n){
    int i = n >> 3;
    int p_i = (i & 7)*4 + (i >> 3);
    return p_i*4 + ((n & 7) >> 1);
}

// ---------------- embedding gather -> bf16 ----------------
__global__ void k_embed(const int* __restrict__ lat,
                        const float* __restrict__ form, const float* __restrict__ lemma,
                        const float* __restrict__ tag,  const float* __restrict__ feats,
                        unsigned short* __restrict__ embB){
    int n = blockIdx.x;
    const int* L = lat + n*11;
    int i0 = L[0], i1 = L[1], i2 = L[2];
    for (int c = threadIdx.x; c < DIN; c += blockDim.x){
        float v;
        if (c < 300)      v = form[i0*300 + c];
        else if (c < 600) v = lemma[i1*300 + (c-300)];
        else if (c < 700) v = tag[i2*100 + (c-600)];
        else {
            float s = 0.f;
            #pragma unroll
            for (int j=0;j<6;++j) s += feats[L[3+j]*100 + (c-700)];
            v = s * (1.0f/6.0f);
        }
        embB[n*DIN + c] = f2bf(v);
    }
}

__global__ void k_f32_to_bf16(const float* __restrict__ src, unsigned short* __restrict__ dst, int n){
    int i = blockIdx.x*blockDim.x + threadIdx.x;
    if (i < n) dst[i] = f2bf(src[i]);
}

// pack Whh for scan v8: worker b=(d*2+p), thread t (0..511): u=t>>2, cs=t&3.
// Gate g, k (0..7): uint4 comp c = f16-pair W[g*256+p*128+u][cs*64 + k*8 + 2c .. +1]
// -> wreg4[(b*32 + g*8 + k)*512 + t]
__global__ void k_pack_whh_v6(const float* __restrict__ wf, const float* __restrict__ wb,
                              uint4* __restrict__ wreg4){
    int id = blockIdx.x*blockDim.x + threadIdx.x;   // 8 blocks x 256
    int b = id >> 9, t = id & 511;
    int d = b >> 1, p = b & 1;
    const float* W = d ? wb : wf;
    int u = t >> 2, cs = t & 3;
    for (int g=0; g<4; ++g){
        const float* R = W + (size_t)(g*256 + p*128 + u)*256 + cs*64;
        for (int k=0; k<8; ++k){
            uint4 v;
            v.x = packh2(R[k*8+0], R[k*8+1]);
            v.y = packh2(R[k*8+2], R[k*8+3]);
            v.z = packh2(R[k*8+4], R[k*8+5]);
            v.w = packh2(R[k*8+6], R[k*8+7]);
            wreg4[((size_t)(b*32 + g*8 + k))*512 + t] = v;
        }
    }
}

// ---------------- bf16 MFMA GEMM: C[M][Nc] = A[M][K] * B[Nc][K]^T (+bias) ----------------
__global__ __launch_bounds__(256) void k_gemm_bf16(const unsigned short* __restrict__ A,
                                                   const unsigned short* __restrict__ B,
                                                   float* __restrict__ C,
                                                   const float* __restrict__ bias,
                                                   int M, int Nc, int K){
    __shared__ unsigned short As[64][40];
    __shared__ unsigned short Bs[64][40];
    int m0 = blockIdx.x*64, n0 = blockIdx.y*64;
    int t = threadIdx.x, w = t>>6, lane = t&63;
    f32x4 acc[4];
    #pragma unroll
    for (int i=0;i<4;++i) acc[i] = (f32x4){0.f,0.f,0.f,0.f};
    int rowl = t>>2, kb0 = (t&3)*8;
    for (int k0=0; k0<K; k0+=32){
        uint4 av;
        int ar = m0 + rowl;
        if (ar < M) av = *(const uint4*)(A + (size_t)ar*K + k0 + kb0);
        else { av.x=av.y=av.z=av.w=0u; }
        *(uint4*)&As[rowl][kb0] = av;
        *(uint4*)&Bs[rowl][kb0] = *(const uint4*)(B + (size_t)(n0+rowl)*K + k0 + kb0);
        __syncthreads();
        int arow = w*16 + (lane&15), kk = (lane>>4)*8;
        bf16x8 af = *(const bf16x8*)&As[arow][kk];
        #pragma unroll
        for (int nt=0;nt<4;++nt){
            bf16x8 bf = *(const bf16x8*)&Bs[nt*16 + (lane&15)][kk];
            acc[nt] = __builtin_amdgcn_mfma_f32_16x16x32_bf16(af, bf, acc[nt], 0,0,0);
        }
        __syncthreads();
    }
    #pragma unroll
    for (int nt=0;nt<4;++nt){
        int col = n0 + nt*16 + (lane&15);
        float bb = bias ? bias[col] : 0.0f;
        #pragma unroll
        for (int r=0;r<4;++r){
            int row = m0 + w*16 + (lane>>4)*4 + r;
            if (row < M) C[(size_t)row*Nc + col] = acc[nt][r] + bb;
        }
    }
}

// ---------------- sequential bi-LSTM scan v8 ----------------
// 4 workers (2 per direction), 512 threads. 32 named uint4 weights/thread.
// Per step: dots -> barrier A -> {wave0: update+xh+flag | wave1: spin+gather} -> barrier D.
// Flags 128B apart; pairs (bid, bid^8) share an XCD.
#define LOADW(g,k) const uint4 W##g##_##k = ldw_opaque(&wreg4[((size_t)(wk*32 + g*8 + k))*512 + t]);

#define GD4(A,Wv,Hv) A=fdot2(Wv.x,Hv.x,A); A=fdot2(Wv.y,Hv.y,A); A=fdot2(Wv.z,Hv.z,A); A=fdot2(Wv.w,Hv.w,A);
#define GDOT(A,g) GD4(A,W##g##_0,hv0) GD4(A,W##g##_1,hv1) GD4(A,W##g##_2,hv2) GD4(A,W##g##_3,hv3) \
                  GD4(A,W##g##_4,hv4) GD4(A,W##g##_5,hv5) GD4(A,W##g##_6,hv6) GD4(A,W##g##_7,hv7)

__global__ __launch_bounds__(512)
__attribute__((amdgpu_waves_per_eu(2,2)))
void k_lstm_scan(const uint4* __restrict__ wreg4,
                 const float* __restrict__ XgF,
                 const float* __restrict__ XgB,
                 int* __restrict__ flg,
                 unsigned* __restrict__ xh,
                 float* __restrict__ encoded,
                 float* __restrict__ h0,
                 float* __restrict__ c0){
    __shared__ uint4 sH4[32];          // 256 h as f16, k-major physical layout
    __shared__ float sG[512];
    int bid = blockIdx.x;
    int d = bid & 7, p = bid >> 3;
    if (d >= 2) return;                // workers: bid 0,8 (d0) / 1,9 (d1); pairs same-XCD
    int wk  = d*2 + p;
    int pwk = d*2 + (1-p);
    int t = threadIdx.x;
    int cs = t & 3;
    int wv = t >> 6;
    int l  = t & 63;
    const float* Xg = d ? XgB : XgF;
    unsigned* sH32 = (unsigned*)sH4;

    LOADW(0,0) LOADW(0,1) LOADW(0,2) LOADW(0,3) LOADW(0,4) LOADW(0,5) LOADW(0,6) LOADW(0,7)
    LOADW(1,0) LOADW(1,1) LOADW(1,2) LOADW(1,3) LOADW(1,4) LOADW(1,5) LOADW(1,6) LOADW(1,7)
    LOADW(2,0) LOADW(2,1) LOADW(2,2) LOADW(2,3) LOADW(2,4) LOADW(2,5) LOADW(2,6) LOADW(2,7)
    LOADW(3,0) LOADW(3,1) LOADW(3,2) LOADW(3,3) LOADW(3,4) LOADW(3,5) LOADW(3,6) LOADW(3,7)

    if (t < 128) sH32[t] = 0u;
    float cA = 0.0f, cB = 0.0f;        // wave0: c for units 2l, 2l+1
    __syncthreads();

    int node  = d ? (NNODE-1) : 0;
    int stepd = d ? -1 : 1;

    for (int s=0; s<NNODE; ++s){
        // wave0 prefetches x-gate inputs for its two units (float2, coalesced)
        float2 xi2, xf2, xg2, xo2;
        if (wv == 0){
            const float* xr = Xg + (size_t)node*G4 + p*128 + 2*l;
            xi2 = *(const float2*)(xr + 0);
            xf2 = *(const float2*)(xr + 256);
            xg2 = *(const float2*)(xr + 512);
            xo2 = *(const float2*)(xr + 768);
        }
        uint4 hv0 = sH4[0*4 + cs];
        uint4 hv1 = sH4[1*4 + cs];
        uint4 hv2 = sH4[2*4 + cs];
        uint4 hv3 = sH4[3*4 + cs];
        uint4 hv4 = sH4[4*4 + cs];
        uint4 hv5 = sH4[5*4 + cs];
        uint4 hv6 = sH4[6*4 + cs];
        uint4 hv7 = sH4[7*4 + cs];
        float a0=0.f,a1=0.f,a2=0.f,a3=0.f;
        GDOT(a0,0)
        GDOT(a1,1)
        GDOT(a2,2)
        GDOT(a3,3)
        a0 += __shfl_xor(a0,1); a0 += __shfl_xor(a0,2);
        a1 += __shfl_xor(a1,1); a1 += __shfl_xor(a1,2);
        a2 += __shfl_xor(a2,1); a2 += __shfl_xor(a2,2);
        a3 += __shfl_xor(a3,1); a3 += __shfl_xor(a3,2);
        if (cs == 0){
            int u = t >> 2;
            sG[u]       = a0;
            sG[128 + u] = a1;
            sG[256 + u] = a2;
            sG[384 + u] = a3;
        }
        __syncthreads();                               // A: sG ready
        if (wv == 0){
            float2 si = *(const float2*)&sG[      2*l];
            float2 sf = *(const float2*)&sG[128 + 2*l];
            float2 sg = *(const float2*)&sG[256 + 2*l];
            float2 so = *(const float2*)&sG[384 + 2*l];
            float giA = si.x + xi2.x, giB = si.y + xi2.y;
            float gfA = sf.x + xf2.x, gfB = sf.y + xf2.y;
            float ggA = sg.x + xg2.x, ggB = sg.y + xg2.y;
            float goA = so.x + xo2.x, goB = so.y + xo2.y;
            float ncA = sigm(gfA)*cA + sigm(giA)*tanhfast(ggA);
            float ncB = sigm(gfB)*cB + sigm(giB)*tanhfast(ggB);
            cA = ncA; cB = ncB;
            float hA = sigm(goA)*tanhfast(ncA);
            float hB = sigm(goB)*tanhfast(ncB);
            unsigned pk = packh2(hA, hB);
            __hip_atomic_store(&xh[(wk*2 + (s&1))*64 + l], pk,
                               __ATOMIC_RELAXED, __HIP_MEMORY_SCOPE_AGENT);
            if (t == 0){
                // release: wave-level vmcnt drain covers all 64 lanes' xh stores
                __hip_atomic_store(&flg[wk*32], s+1, __ATOMIC_RELEASE, __HIP_MEMORY_SCOPE_AGENT);
            }
            sH32[dwslot(p*128 + 2*l)] = pk;
            float2 h2; h2.x = hA; h2.y = hB;
            *(float2*)&encoded[(size_t)node*DHID + d*HENC + p*128 + 2*l] = h2;
            if (s == NNODE-1){
                *(float2*)&h0[d*HENC + p*128 + 2*l] = h2;
                float2 c2; c2.x = ncA; c2.y = ncB;
                *(float2*)&c0[d*HENC + p*128 + 2*l] = c2;
            }
        } else if (wv == 1){
            long iters = 0;
            while (__hip_atomic_load(&flg[pwk*32], __ATOMIC_ACQUIRE, __HIP_MEMORY_SCOPE_AGENT) < s+1){
                if (++iters > (1L<<27)) break;         // safety valve vs. hang
            }
            unsigned pk = __hip_atomic_load(&xh[(pwk*2 + (s&1))*64 + l],
                                            __ATOMIC_RELAXED, __HIP_MEMORY_SCOPE_AGENT);
            sH32[dwslot((1-p)*128 + 2*l)] = pk;
        }
        __syncthreads();                               // D: full h ready for next step
        node += stepd;
    }
}

// Kd = dec_whh @ h0 + dec_b
__global__ void k_dec_const(const float* __restrict__ dec_whh, const float* __restrict__ dec_b,
                            const float* __restrict__ h0, float* __restrict__ Kd){
    __shared__ float sh[512];
    int t = threadIdx.x;
    int r = blockIdx.x*256 + t;
    sh[t] = h0[t]; sh[256+t] = h0[256+t];
    __syncthreads();
    float a = 0.f;
    const float* Wr = dec_whh + (size_t)r*512;
    for (int k=0;k<512;++k) a += Wr[k]*sh[k];
    Kd[r] = a + dec_b[r];
}

// decoder h for every possible ptr node
__global__ void k_hall(const float* __restrict__ G, const float* __restrict__ Kd,
                       const float* __restrict__ c0, float* __restrict__ Hall){
    int n = blockIdx.x, u = threadIdx.x;
    const float* g = G + (size_t)n*DG4;
    float gi = g[u]        + Kd[u];
    float gf = g[512+u]    + Kd[512+u];
    float gg = g[1024+u]   + Kd[1024+u];
    float go = g[1536+u]   + Kd[1536+u];
    float c  = sigm(gf)*c0[u] + sigm(gi)*tanhfast(gg);
    Hall[(size_t)n*DHID + u] = sigm(go)*tanhfast(c);
}

// S[i][p][c] = encoded[cand(i,c)] . Hall[prev(i,p)]
__global__ __launch_bounds__(256) void k_scores(const float* __restrict__ encoded,
                                                const float* __restrict__ Hall,
                                                float* __restrict__ S){
    __shared__ float sE[8][512];
    __shared__ float sHp[8][512];
    int i = blockIdx.x, t = threadIdx.x;
    for (int idx = t; idx < 8*512; idx += 256){
        int r = idx >> 9, c = idx & 511;
        int cand = 1 + i*8 + r;
        sE[r][c] = encoded[(size_t)cand*DHID + c];
        int prev = (i==0) ? 0 : (1 + (i-1)*8 + r);
        sHp[r][c] = Hall[(size_t)prev*DHID + c];
    }
    __syncthreads();
    int w = t>>6, lane = t&63;
    for (int q=0;q<16;++q){
        int pi = w*16 + q, p = pi>>3, c = pi&7;
        float v = 0.f;
        #pragma unroll
        for (int j=0;j<8;++j) v += sE[c][lane*8+j]*sHp[p][lane*8+j];
        #pragma unroll
        for (int off=32; off; off>>=1) v += __shfl_xor(v, off);
        if (lane==0) S[i*64 + p*8 + c] = v;
    }
}

// sequential pointer chain + loss
__global__ __launch_bounds__(256) void k_decode(const float* __restrict__ S, float* __restrict__ out){
    __shared__ float nll[2048];
    __shared__ int   cst[2048];
    __shared__ int   path[256];
    __shared__ float wsum[4];
    int t = threadIdx.x;
    for (int p=0;p<8;++p){
        const float* s = S + t*64 + p*8;
        float m = s[0]; int am = 0;
        #pragma unroll
        for (int c=1;c<8;++c){ float v = s[c]; if (v > m){ m = v; am = c; } }
        float e = 0.f;
        #pragma unroll
        for (int c=0;c<8;++c) e += __expf(s[c]-m);
        float lse = m + __logf(e);
        nll[t*8+p] = lse - s[0];
        cst[t*8+p] = am;
    }
    __syncthreads();
    if (t == 0){
        int p = 0;
        for (int i=0;i<256;++i){
            int idx = i*8 + p;
            path[i] = idx;
            int c = cst[idx];
            out[i+1] = (float)(1 + i*8 + c);
            p = c;
        }
        out[0] = 0.0f;
    }
    __syncthreads();
    float v = nll[path[t]];
    #pragma unroll
    for (int off=32; off; off>>=1) v += __shfl_xor(v, off);
    if ((t&63)==0) wsum[t>>6] = v;
    __syncthreads();
    if (t==0) out[257] = (wsum[0]+wsum[1]+wsum[2]+wsum[3]) * (1.0f/256.0f);
}

extern "C" void kernel_launch(void* const* d_in, const int* in_sizes, int n_in,
                              void* d_out, int out_size, void* d_ws, size_t ws_size,
                              hipStream_t stream){
    (void)in_sizes; (void)n_in; (void)out_size; (void)ws_size;
    const int*   lattice  = (const int*)  d_in[0];
    const float* form     = (const float*)d_in[2];
    const float* lemma    = (const float*)d_in[3];
    const float* tag      = (const float*)d_in[4];
    const float* feats    = (const float*)d_in[5];
    const float* wih_f    = (const float*)d_in[6];
    const float* whh_f    = (const float*)d_in[7];
    const float* b_f      = (const float*)d_in[8];
    const float* wih_b    = (const float*)d_in[9];
    const float* whh_b    = (const float*)d_in[10];
    const float* b_b      = (const float*)d_in[11];
    const float* dwih     = (const float*)d_in[12];
    const float* dwhh     = (const float*)d_in[13];
    const float* db       = (const float*)d_in[14];
    float* out = (float*)d_out;

    char* ws = (char*)d_ws;
    size_t o = 0;
    auto alloc = [&](size_t bytes)->char*{ char* p = ws + o; o = (o + bytes + 255) & ~(size_t)255; return p; };
    int*            flg    = (int*)alloc(512);                      // 4 flags, 128B apart
    unsigned*       xh     = (unsigned*)alloc(4*2*64*4);            // [4][2][64] packed f16x2
    unsigned short* embB   = (unsigned short*)alloc((size_t)NNODE*DIN*2);
    unsigned short* wihfB  = (unsigned short*)alloc((size_t)G4*DIN*2);
    unsigned short* wihbB  = (unsigned short*)alloc((size_t)G4*DIN*2);
    unsigned short* dwihB  = (unsigned short*)alloc((size_t)DG4*DIN*2);
    uint4*          wreg4  = (uint4*)alloc((size_t)4*32*512*16);
    float*          XgF    = (float*)alloc((size_t)NNODE*G4*4);
    float*          XgB    = (float*)alloc((size_t)NNODE*G4*4);
    float*          Graw   = (float*)alloc((size_t)NNODE*DG4*4);
    float*          enc    = (float*)alloc((size_t)NNODE*DHID*4);
    float*          h0     = (float*)alloc(512*4);
    float*          c0     = (float*)alloc(512*4);
    float*          Kd     = (float*)alloc(2048*4);
    float*          Hall   = (float*)alloc((size_t)NNODE*DHID*4);
    float*          Sbuf   = (float*)alloc((size_t)256*64*4);

    // reset sync state every launch (graph-capture safe)
    hipMemsetAsync(d_ws, 0, 8192, stream);

    k_f32_to_bf16<<<(G4*DIN+255)/256, 256, 0, stream>>>(wih_f, wihfB, G4*DIN);
    k_f32_to_bf16<<<(G4*DIN+255)/256, 256, 0, stream>>>(wih_b, wihbB, G4*DIN);
    k_f32_to_bf16<<<(DG4*DIN+255)/256, 256, 0, stream>>>(dwih, dwihB, DG4*DIN);
    k_pack_whh_v6<<<8, 256, 0, stream>>>(whh_f, whh_b, wreg4);
    k_embed<<<NNODE, 256, 0, stream>>>(lattice, form, lemma, tag, feats, embB);

    dim3 gE((NNODE+63)/64, G4/64);
    k_gemm_bf16<<<gE, 256, 0, stream>>>(embB, wihfB, XgF, b_f, NNODE, G4, DIN);
    k_gemm_bf16<<<gE, 256, 0, stream>>>(embB, wihbB, XgB, b_b, NNODE, G4, DIN);
    dim3 gD((NNODE+63)/64, DG4/64);
    k_gemm_bf16<<<gD, 256, 0, stream>>>(embB, dwihB, Graw, nullptr, NNODE, DG4, DIN);

    k_lstm_scan<<<16, 512, 0, stream>>>(wreg4, XgF, XgB, flg, xh, enc, h0, c0);

    k_dec_const<<<8, 256, 0, stream>>>(dwhh, db, h0, Kd);
    k_hall<<<NNODE, 512, 0, stream>>>(Graw, Kd, c0, Hall);
    k_scores<<<256, 256, 0, stream>>>(enc, Hall, Sbuf);
    k_decode<<<1, 256, 0, stream>>>(Sbuf, out);
}